// Round 3
// baseline (955.592 us; speedup 1.0000x reference)
//
#include <hip/hip_runtime.h>

#define HDIM 768

constexpr int RPB   = 64;          // rows per block
constexpr int SPL   = 4;           // K-way split across threads (256 = 64 rows x 4 splits)
constexpr int KPC   = 64;          // k-columns staged per chunk (16 per split)
constexpr int NCH   = HDIM / KPC;  // 12 chunks
constexpr int PITCH = KPC + 4;     // 68 floats -> 272B pitch (empirically conflict-free, R1/R2)

__device__ __forceinline__ void dot4(float& a, const float4 xv,
                                     const float* __restrict__ Wrow, int kb) {
    // kb carries an opaque VGPR zero -> keeps W on the VECTOR memory path
    // (global_load_dwordx4 broadcast, in-order vmcnt) instead of s_load batches
    // that blew the SGPR budget and forced lgkmcnt(0) drains (R1 -> R2 win).
    const float4 w = *(const float4*)(Wrow + kb);
    a = fmaf(xv.x, w.x, a);
    a = fmaf(xv.y, w.y, a);
    a = fmaf(xv.z, w.z, a);
    a = fmaf(xv.w, w.w, a);
}

__global__ __launch_bounds__(256, 6)
void hier_fused(const float* __restrict__ x,
                const float* __restrict__ Wa,  const float* __restrict__ ba,
                const float* __restrict__ Wb,  const float* __restrict__ bb,
                const float* __restrict__ Wc1, const float* __restrict__ bc1,
                const float* __restrict__ Wc2, const float* __restrict__ bc2,
                const float* __restrict__ Wc3, const float* __restrict__ bc3,
                const float* __restrict__ Wc4, const float* __restrict__ bc4,
                float* __restrict__ out, int B)
{
    __shared__ float xs[RPB * PITCH];   // 64*68*4 = 17408 B -> ~6 blocks/CU w/ launch_bounds

    const int t       = threadIdx.x;
    const int r       = t & (RPB - 1);  // row within block
    const int s       = t >> 6;         // K-split 0..3; whole wave shares one split
    const int rowBase = blockIdx.x * RPB;

    int vz;
    asm("v_mov_b32 %0, 0" : "=v"(vz));  // opaque zero: defeats scalar-load promotion

    float acc[17];
#pragma unroll
    for (int j = 0; j < 17; ++j) acc[j] = 0.f;

    // staging map: 16 consecutive lanes cover one row's 64-float chunk slice
    const int col4 = (t & 15) * 4;      // 0..60
    const int grp  = t >> 4;            // 0..15

    float4 p[4];                        // register double-buffer for next chunk

    auto fetch = [&](int c) {           // issue global loads for chunk c -> p[]
#pragma unroll
        for (int i = 0; i < 4; ++i) {
            int r2  = grp + i * 16;     // 0..63
            int row = rowBase + r2;
            if (row >= B) row = B - 1;  // safe clamp (grid divides B exactly)
            p[i] = *(const float4*)&x[(size_t)row * HDIM + c * KPC + col4];
        }
    };
    auto store = [&]() {                // p[] -> LDS
#pragma unroll
        for (int i = 0; i < 4; ++i)
            *(float4*)&xs[(grp + i * 16) * PITCH + col4] = p[i];
    };

    fetch(0);
    store();
    __syncthreads();
    fetch(1);                           // prefetch: HBM latency hides behind compute(0)

    const float* xr = &xs[r * PITCH + s * 16];

    for (int c = 0; c < NCH; ++c) {
        // global k for (c, s, kk) = c*64 + s*16 + kk  (each k covered exactly once)
        const int kbase = c * KPC + s * 16 + vz;
#pragma unroll 2
        for (int kk = 0; kk < 16; kk += 4) {
            const float4 xv = *(const float4*)(xr + kk);
            const int kb = kbase + kk;
            dot4(acc[0],  xv, Wa,              kb);
            dot4(acc[1],  xv, Wa  +     HDIM,  kb);
            dot4(acc[2],  xv, Wb,              kb);
            dot4(acc[3],  xv, Wb  +     HDIM,  kb);
            dot4(acc[4],  xv, Wb  + 2 * HDIM,  kb);
            dot4(acc[5],  xv, Wb  + 3 * HDIM,  kb);
            dot4(acc[6],  xv, Wc1,             kb);
            dot4(acc[7],  xv, Wc1 +     HDIM,  kb);
            dot4(acc[8],  xv, Wc2,             kb);
            dot4(acc[9],  xv, Wc2 +     HDIM,  kb);
            dot4(acc[10], xv, Wc2 + 2 * HDIM,  kb);
            dot4(acc[11], xv, Wc3,             kb);
            dot4(acc[12], xv, Wc3 +     HDIM,  kb);
            dot4(acc[13], xv, Wc3 + 2 * HDIM,  kb);
            dot4(acc[14], xv, Wc3 + 3 * HDIM,  kb);
            dot4(acc[15], xv, Wc4,             kb);
            dot4(acc[16], xv, Wc4 +     HDIM,  kb);
        }
        if (c + 1 < NCH) {
            __syncthreads();            // all waves done reading chunk c
            store();                    // write prefetched chunk c+1
            __syncthreads();
            if (c + 2 < NCH) fetch(c + 2);
        }
    }

    // ---- reduce the 4 K-split partials through LDS (xs is dead now) ----
    __syncthreads();
    if (s > 0) {
#pragma unroll
        for (int j = 0; j < 17; ++j)
            xs[((s - 1) * RPB + r) * 17 + j] = acc[j];
    }
    __syncthreads();
    if (s != 0) return;
#pragma unroll
    for (int ss = 0; ss < 3; ++ss)
#pragma unroll
        for (int j = 0; j < 17; ++j)
            acc[j] += xs[(ss * RPB + r) * 17 + j];

    const int row = rowBase + r;
    if (row >= B) return;

    // taskA head + route (fp32-exact routing)
    const float oa0 = acc[0] + ba[0];
    const float oa1 = acc[1] + ba[1];
    const bool active = oa1 > oa0;               // argmax != 0 (first-max tie -> 0)

    // taskB head
    const float tb0 = acc[2] + bb[0];
    const float tb1 = acc[3] + bb[1];
    const float tb2 = acc[4] + bb[2];
    const float tb3 = acc[5] + bb[3];
    int   pidx = 0;
    float m = tb0;
    if (tb1 > m) { m = tb1; pidx = 1; }          // strict > == first-occurrence argmax
    if (tb2 > m) { m = tb2; pidx = 2; }
    if (tb3 > m) { m = tb3; pidx = 3; }

    // out_a [B,2] at offset 0
    float* oa = out + (size_t)2 * row;
    oa[0] = oa0;
    oa[1] = oa1;

    // out_b [B,5] at offset 2B
    float* ob = out + (size_t)2 * B + (size_t)5 * row;
    ob[0] = 0.f;
    ob[1] = active ? tb0 : 0.f;
    ob[2] = active ? tb1 : 0.f;
    ob[3] = active ? tb2 : 0.f;
    ob[4] = active ? tb3 : 0.f;

    // out_c [B,11] at offset 7B; spans h0:[0,2) h1:[2,5) h2:[5,9) h3:[9,11)
    const bool m0 = active && (pidx == 0);
    const bool m1 = active && (pidx == 1);
    const bool m2 = active && (pidx == 2);
    const bool m3 = active && (pidx == 3);
    float* oc = out + (size_t)7 * B + (size_t)11 * row;
    oc[0]  = m0 ? acc[6]  + bc1[0] : 0.f;
    oc[1]  = m0 ? acc[7]  + bc1[1] : 0.f;
    oc[2]  = m1 ? acc[8]  + bc2[0] : 0.f;
    oc[3]  = m1 ? acc[9]  + bc2[1] : 0.f;
    oc[4]  = m1 ? acc[10] + bc2[2] : 0.f;
    oc[5]  = m2 ? acc[11] + bc3[0] : 0.f;
    oc[6]  = m2 ? acc[12] + bc3[1] : 0.f;
    oc[7]  = m2 ? acc[13] + bc3[2] : 0.f;
    oc[8]  = m2 ? acc[14] + bc3[3] : 0.f;
    oc[9]  = m3 ? acc[15] + bc4[0] : 0.f;
    oc[10] = m3 ? acc[16] + bc4[1] : 0.f;
}

extern "C" void kernel_launch(void* const* d_in, const int* in_sizes, int n_in,
                              void* d_out, int out_size, void* d_ws, size_t ws_size,
                              hipStream_t stream) {
    const float* x   = (const float*)d_in[0];
    const float* Wa  = (const float*)d_in[1];
    const float* ba  = (const float*)d_in[2];
    const float* Wb  = (const float*)d_in[3];
    const float* bb  = (const float*)d_in[4];
    const float* Wc1 = (const float*)d_in[5];
    const float* bc1 = (const float*)d_in[6];
    const float* Wc2 = (const float*)d_in[7];
    const float* bc2 = (const float*)d_in[8];
    const float* Wc3 = (const float*)d_in[9];
    const float* bc3 = (const float*)d_in[10];
    const float* Wc4 = (const float*)d_in[11];
    const float* bc4 = (const float*)d_in[12];

    const int B  = in_sizes[0] / HDIM;
    const int nb = (B + RPB - 1) / RPB;

    hipLaunchKernelGGL(hier_fused, dim3(nb), dim3(256), 0, stream,
                       x, Wa, ba, Wb, bb, Wc1, bc1, Wc2, bc2, Wc3, bc3, Wc4, bc4,
                       (float*)d_out, B);
}

// Round 4
// 764.423 us; speedup vs baseline: 1.2501x; 1.2501x over previous
//
#include <hip/hip_runtime.h>

#define HDIM 768

constexpr int RPB   = 64;          // rows per block
constexpr int KPC   = 64;          // k-columns staged per chunk (16 per split)
constexpr int NCH   = HDIM / KPC;  // 12 chunks
constexpr int PITCH = KPC + 4;     // 68 floats -> 272B pitch (measured conflict-free, R1/R2)
constexpr int BUFSZ = RPB * PITCH; // 4352 floats per buffer

__device__ __forceinline__ void dot4(float& a, const float4 xv,
                                     const float* __restrict__ Wrow, int kb) {
    // kb carries an opaque VGPR zero -> keeps W on the VECTOR memory path
    // (global_load_dwordx4 broadcast, in-order vmcnt) instead of s_load batches
    // that blew the SGPR budget and forced lgkmcnt(0) drains (R1 -> R2 win).
    const float4 w = *(const float4*)(Wrow + kb);
    a = fmaf(xv.x, w.x, a);
    a = fmaf(xv.y, w.y, a);
    a = fmaf(xv.z, w.z, a);
    a = fmaf(xv.w, w.w, a);
}

// launch_bounds(256,4): 128-VGPR cap. (256,6) in R3 capped at ~85 and spilled
// acc[]+p[] to scratch -> 716 MB of WRITE_SIZE. Do not raise without checking
// VGPR count stays spill-free.
__global__ __launch_bounds__(256, 4)
void hier_fused(const float* __restrict__ x,
                const float* __restrict__ Wa,  const float* __restrict__ ba,
                const float* __restrict__ Wb,  const float* __restrict__ bb,
                const float* __restrict__ Wc1, const float* __restrict__ bc1,
                const float* __restrict__ Wc2, const float* __restrict__ bc2,
                const float* __restrict__ Wc3, const float* __restrict__ bc3,
                const float* __restrict__ Wc4, const float* __restrict__ bc4,
                float* __restrict__ out, int B)
{
    __shared__ float xs[2 * BUFSZ];  // 34816 B double-buffer -> 4 blocks/CU

    const int t       = threadIdx.x;
    const int r       = t & (RPB - 1);  // row within block
    const int s       = t >> 6;         // K-split 0..3; whole wave shares one split
    const int rowBase = blockIdx.x * RPB;

    int vz;
    asm("v_mov_b32 %0, 0" : "=v"(vz));  // opaque zero: defeats scalar-load promotion

    float acc[17];
#pragma unroll
    for (int j = 0; j < 17; ++j) acc[j] = 0.f;

    // staging map: 16 consecutive lanes cover one row's 64-float chunk slice
    const int col4 = (t & 15) * 4;      // 0..60
    const int grp  = t >> 4;            // 0..15

    float4 p[4];                        // register prefetch buffer for next chunk

    auto fetch = [&](int c) {           // issue global loads for chunk c -> p[]
#pragma unroll
        for (int i = 0; i < 4; ++i) {
            int r2  = grp + i * 16;     // 0..63
            int row = rowBase + r2;
            if (row >= B) row = B - 1;  // safe clamp (grid divides B exactly)
            p[i] = *(const float4*)&x[(size_t)row * HDIM + c * KPC + col4];
        }
    };
    auto store = [&](int buf) {         // p[] -> LDS buffer `buf`
        float* dst = &xs[buf * BUFSZ];
#pragma unroll
        for (int i = 0; i < 4; ++i)
            *(float4*)&dst[(grp + i * 16) * PITCH + col4] = p[i];
    };

    fetch(0);
    store(0);
    __syncthreads();
    fetch(1);                           // HBM latency hides behind compute(0)

    for (int c = 0; c < NCH; ++c) {
        const float* xr    = &xs[(c & 1) * BUFSZ + r * PITCH + s * 16];
        const int    kbase = c * KPC + s * 16 + vz;
#pragma unroll 2
        for (int kk = 0; kk < 16; kk += 4) {
            const float4 xv = *(const float4*)(xr + kk);
            const int kb = kbase + kk;
            dot4(acc[0],  xv, Wa,              kb);
            dot4(acc[1],  xv, Wa  +     HDIM,  kb);
            dot4(acc[2],  xv, Wb,              kb);
            dot4(acc[3],  xv, Wb  +     HDIM,  kb);
            dot4(acc[4],  xv, Wb  + 2 * HDIM,  kb);
            dot4(acc[5],  xv, Wb  + 3 * HDIM,  kb);
            dot4(acc[6],  xv, Wc1,             kb);
            dot4(acc[7],  xv, Wc1 +     HDIM,  kb);
            dot4(acc[8],  xv, Wc2,             kb);
            dot4(acc[9],  xv, Wc2 +     HDIM,  kb);
            dot4(acc[10], xv, Wc2 + 2 * HDIM,  kb);
            dot4(acc[11], xv, Wc3,             kb);
            dot4(acc[12], xv, Wc3 +     HDIM,  kb);
            dot4(acc[13], xv, Wc3 + 2 * HDIM,  kb);
            dot4(acc[14], xv, Wc3 + 3 * HDIM,  kb);
            dot4(acc[15], xv, Wc4,             kb);
            dot4(acc[16], xv, Wc4 +     HDIM,  kb);
        }
        if (c + 1 < NCH) {
            // writes go to the OTHER buffer; readers of chunk c are untouched.
            // One barrier per chunk: a wave can only reach store(c+2) into
            // buf[c&1] after this barrier, by which time all waves left
            // compute(c).
            store((c + 1) & 1);
            __syncthreads();
            if (c + 2 < NCH) fetch(c + 2);
        }
    }

    // ---- reduce the 4 K-split partials through LDS (xs is dead now) ----
    __syncthreads();
    if (s > 0) {
#pragma unroll
        for (int j = 0; j < 17; ++j)
            xs[((s - 1) * RPB + r) * 17 + j] = acc[j];
    }
    __syncthreads();
    if (s != 0) return;
#pragma unroll
    for (int ss = 0; ss < 3; ++ss)
#pragma unroll
        for (int j = 0; j < 17; ++j)
            acc[j] += xs[(ss * RPB + r) * 17 + j];

    const int row = rowBase + r;
    if (row >= B) return;

    // taskA head + route (fp32-exact routing)
    const float oa0 = acc[0] + ba[0];
    const float oa1 = acc[1] + ba[1];
    const bool active = oa1 > oa0;               // argmax != 0 (first-max tie -> 0)

    // taskB head
    const float tb0 = acc[2] + bb[0];
    const float tb1 = acc[3] + bb[1];
    const float tb2 = acc[4] + bb[2];
    const float tb3 = acc[5] + bb[3];
    int   pidx = 0;
    float m = tb0;
    if (tb1 > m) { m = tb1; pidx = 1; }          // strict > == first-occurrence argmax
    if (tb2 > m) { m = tb2; pidx = 2; }
    if (tb3 > m) { m = tb3; pidx = 3; }

    // out_a [B,2] at offset 0
    float* oa = out + (size_t)2 * row;
    oa[0] = oa0;
    oa[1] = oa1;

    // out_b [B,5] at offset 2B
    float* ob = out + (size_t)2 * B + (size_t)5 * row;
    ob[0] = 0.f;
    ob[1] = active ? tb0 : 0.f;
    ob[2] = active ? tb1 : 0.f;
    ob[3] = active ? tb2 : 0.f;
    ob[4] = active ? tb3 : 0.f;

    // out_c [B,11] at offset 7B; spans h0:[0,2) h1:[2,5) h2:[5,9) h3:[9,11)
    const bool m0 = active && (pidx == 0);
    const bool m1 = active && (pidx == 1);
    const bool m2 = active && (pidx == 2);
    const bool m3 = active && (pidx == 3);
    float* oc = out + (size_t)7 * B + (size_t)11 * row;
    oc[0]  = m0 ? acc[6]  + bc1[0] : 0.f;
    oc[1]  = m0 ? acc[7]  + bc1[1] : 0.f;
    oc[2]  = m1 ? acc[8]  + bc2[0] : 0.f;
    oc[3]  = m1 ? acc[9]  + bc2[1] : 0.f;
    oc[4]  = m1 ? acc[10] + bc2[2] : 0.f;
    oc[5]  = m2 ? acc[11] + bc3[0] : 0.f;
    oc[6]  = m2 ? acc[12] + bc3[1] : 0.f;
    oc[7]  = m2 ? acc[13] + bc3[2] : 0.f;
    oc[8]  = m2 ? acc[14] + bc3[3] : 0.f;
    oc[9]  = m3 ? acc[15] + bc4[0] : 0.f;
    oc[10] = m3 ? acc[16] + bc4[1] : 0.f;
}

extern "C" void kernel_launch(void* const* d_in, const int* in_sizes, int n_in,
                              void* d_out, int out_size, void* d_ws, size_t ws_size,
                              hipStream_t stream) {
    const float* x   = (const float*)d_in[0];
    const float* Wa  = (const float*)d_in[1];
    const float* ba  = (const float*)d_in[2];
    const float* Wb  = (const float*)d_in[3];
    const float* bb  = (const float*)d_in[4];
    const float* Wc1 = (const float*)d_in[5];
    const float* bc1 = (const float*)d_in[6];
    const float* Wc2 = (const float*)d_in[7];
    const float* bc2 = (const float*)d_in[8];
    const float* Wc3 = (const float*)d_in[9];
    const float* bc3 = (const float*)d_in[10];
    const float* Wc4 = (const float*)d_in[11];
    const float* bc4 = (const float*)d_in[12];

    const int B  = in_sizes[0] / HDIM;
    const int nb = (B + RPB - 1) / RPB;

    hipLaunchKernelGGL(hier_fused, dim3(nb), dim3(256), 0, stream,
                       x, Wa, ba, Wb, bb, Wc1, bc1, Wc2, bc2, Wc3, bc3, Wc4, bc4,
                       (float*)d_out, B);
}